// Round 6
// baseline (838.650 us; speedup 1.0000x reference)
//
#include <hip/hip_runtime.h>
#include <math.h>

#define TT 2048
#define BBATCH 256
#define DDIM 57
#define NROWS (BBATCH*TT)
#define NF 524288.0f
#define U 8

__device__ __forceinline__ float bcastl(float v, int k) {
  return __uint_as_float((unsigned)__builtin_amdgcn_readlane((int)__float_as_uint(v), k));
}
__device__ __forceinline__ float rcpf(float x) { return __builtin_amdgcn_rcpf(x); }
__device__ __forceinline__ float med3f(float x, float lo, float hi) {
  return __builtin_amdgcn_fmed3f(x, lo, hi);
}

// Pade[7/6] of tanh (exact continued-fraction coeffs), |t|<=4 after clamp:
// tanh(t) ~= t*(135135+17325u+378u^2+u^3)/(135135+62370u+3150u^2+28u^3), u=t^2
// max err 1.5e-5 inside, <=7e-4 from the +-4 clamp. FMA-only + ONE v_rcp.
__device__ __forceinline__ float pade_tanh(float x) {
  float t = med3f(x, -4.f, 4.f);
  float u = t * t;
  float n = fmaf(fmaf(u + 378.f, u, 17325.f), u, 135135.f) * t;
  float d = fmaf(fmaf(fmaf(28.f, u, 3150.f), u, 62370.f), u, 135135.f);
  return n * rcpf(d);
}

// quad_perm broadcast: all 4 lanes of each quad get lane (PAT&3)'s value.
template<int PAT>
__device__ __forceinline__ float quadb(float v) {
  return __int_as_float(__builtin_amdgcn_update_dpp(0, __float_as_int(v), PAT, 0xF, 0xF, true));
}

__global__ void zero_accum_k(float* accum) {
  accum[threadIdx.x] = 0.f;
}

// xg0[r, lane] = fac(g) * (dot(x[r,:], W_ih0[g,:]) + b_ih0[g]+b_hh0[g])
// g = (lane&3)*16 + (lane>>2); fac = 0.5 for sigmoid rows (i,f,o) — folds the
// sigma(x)=0.5+0.5*tanh(x/2) argument halving into the weights — 1.0 for g rows.
__global__ __launch_bounds__(256) void xg0_gemm_k(
    const float* __restrict__ x, const float* __restrict__ Wih,
    const float* __restrict__ bih, const float* __restrict__ bhh,
    float* __restrict__ xg0)
{
  const int lane = threadIdx.x & 63;
  const int g = (lane & 3) * 16 + (lane >> 2);
  const float fac = ((lane & 3) == 2) ? 1.f : 0.5f;
  const int wid  = blockIdx.x * (blockDim.x >> 6) + (threadIdx.x >> 6);
  const int nw   = gridDim.x * (blockDim.x >> 6);
  float w[DDIM];
  #pragma unroll
  for (int d = 0; d < DDIM; ++d) w[d] = fac * Wih[g*DDIM + d];
  const float bias = fac * (bih[g] + bhh[g]);

  int r = wid;
  float xv = 0.f;
  if (r < NROWS && lane < DDIM)
    xv = x[(size_t)__builtin_amdgcn_readfirstlane(r) * DDIM + lane];
  for (; r < NROWS; r += nw) {
    const int rn = r + nw;
    float xn = 0.f;
    if (rn < NROWS && lane < DDIM)                  // prefetch next row
      xn = x[(size_t)__builtin_amdgcn_readfirstlane(rn) * DDIM + lane];
    float a0 = bias, a1 = 0.f, a2 = 0.f, a3 = 0.f;
    #pragma unroll
    for (int d = 0; d < 56; d += 4) {
      a0 += w[d]   * bcastl(xv, d);
      a1 += w[d+1] * bcastl(xv, d+1);
      a2 += w[d+2] * bcastl(xv, d+2);
      a3 += w[d+3] * bcastl(xv, d+3);
    }
    a0 += w[56] * bcastl(xv, 56);
    xg0[(size_t)__builtin_amdgcn_readfirstlane(r) * 64 + lane] = (a0 + a1) + (a2 + a3);
    xv = xn;
  }
}

// Layer-pipelined scan, U=8 steps/slot, 3 waves/block (wave w = layer w,
// lagging w slots). Lane layout: ch=lane>>2, gate=lane&3 (i,f,g,o).
// Activations are FMA-only Pade tanh (1 v_rcp each) — per-step serial chain
// has 2 transcendentals instead of 4 (R5 showed latency-bound, not issue-bound).
__global__ __launch_bounds__(192, 1) void lstm_scan_pipe_k(
    const float* __restrict__ xg0,
    const int*   __restrict__ lengths,
    const float* __restrict__ Whh0,
    const float* __restrict__ Wih1, const float* __restrict__ Whh1,
    const float* __restrict__ bih1, const float* __restrict__ bhh1,
    const float* __restrict__ Wih2, const float* __restrict__ Whh2,
    const float* __restrict__ bih2, const float* __restrict__ bhh2,
    float* __restrict__ h2buf, float* __restrict__ accum)
{
  const int tid  = threadIdx.x;
  const int wave = tid >> 6;
  const int lane = tid & 63;
  const int gt   = lane & 3;       // 0=i 1=f 2=g 3=o
  const int ch   = lane >> 2;      // channel 0..15
  const int g    = gt*16 + ch;     // weight row (PyTorch i,f,g,o blocks)
  const int b    = blockIdx.x;
  const int len  = lengths[b];
  const bool isg = (gt == 2);
  const float fac = isg ? 1.f : 0.5f;   // sigma arg halving folded into weights
  const float mg = isg ? 1.f : 0.5f;    // act = th*mg + ag
  const float ag = isg ? 0.f : 0.5f;

  __shared__ float lds_h0[2][U][16];
  __shared__ float lds_h1[2][U][16];

  float wa[16], wb[16];
  float bias = 0.f;
  if (wave == 0) {
    #pragma unroll
    for (int k = 0; k < 16; ++k) { wb[k] = fac * Whh0[g*16 + k]; wa[k] = 0.f; }
  } else if (wave == 1) {
    #pragma unroll
    for (int k = 0; k < 16; ++k) { wa[k] = fac * Wih1[g*16 + k]; wb[k] = fac * Whh1[g*16 + k]; }
    bias = fac * (bih1[g] + bhh1[g]);
  } else {
    #pragma unroll
    for (int k = 0; k < 16; ++k) { wa[k] = fac * Wih2[g*16 + k]; wb[k] = fac * Whh2[g*16 + k]; }
    bias = fac * (bih2[g] + bhh2[g]);
  }

  float hs = 0.f, cs = 0.f;
  float sum = 0.f, sq = 0.f;
  const int base = b*TT*64 + lane;
  float* __restrict__ h2row = h2buf + (size_t)b*TT*16;

  auto lstm_update = [&](float dot) {
    float th  = pade_tanh(dot);           // dot pre-scaled: sigma rows x0.5
    float act = fmaf(th, mg, ag);         // sigmoid, or tanh for g-gate
    float gi = quadb<0x00>(act);
    float gf = quadb<0x55>(act);
    float gg = quadb<0xAA>(act);
    float go = quadb<0xFF>(act);
    cs = fmaf(gf, cs, gi*gg);
    hs = go * pade_tanh(cs);
  };
  auto owndot = [&](float seed) {         // seed + Whh' . h_own (readlane)
    float a0 = seed, a1 = 0.f, a2 = 0.f, a3 = 0.f;
    #pragma unroll
    for (int k = 0; k < 16; k += 4) {     // h[k] lives on lane 4k
      a0 += wb[k]   * bcastl(hs, 4*k);
      a1 += wb[k+1] * bcastl(hs, 4*k+4);
      a2 += wb[k+2] * bcastl(hs, 4*k+8);
      a3 += wb[k+3] * bcastl(hs, 4*k+12);
    }
    return (a0 + a1) + (a2 + a3);
  };
  // bias + Wih' . hin, hin as full register vector (no readlane)
  auto indot = [&](const float* hin) {
    float a0 = bias, a1 = 0.f, a2 = 0.f, a3 = 0.f;
    #pragma unroll
    for (int k = 0; k < 16; k += 4) {
      a0 += wa[k]   * hin[k];
      a1 += wa[k+1] * hin[k+1];
      a2 += wa[k+2] * hin[k+2];
      a3 += wa[k+3] * hin[k+3];
    }
    return (a0 + a1) + (a2 + a3);
  };

  const int NS = (len + U - 1) / U;
  const int S  = NS + 2;

  float cur[U], nxt[U];
  if (wave == 0) {
    #pragma unroll
    for (int j = 0; j < U; ++j) cur[j] = xg0[base + j*64];
    #pragma unroll
    for (int j = 0; j < U; ++j) {
      int ip = U + j; ip = ip > TT-1 ? TT-1 : ip;
      nxt[j] = xg0[base + ip*64];
    }
  }

  for (int s = 0; s < S; ++s) {
    const int p = s & 1, q = p ^ 1;
    if (wave == 0) {
      if (s < NS) {
        float ld[U];
        #pragma unroll
        for (int j = 0; j < U; ++j) {
          int ip = (s + 2)*U + j; ip = ip > TT-1 ? TT-1 : ip;
          ld[j] = xg0[base + ip*64];      // slot s+2; lands well before use
        }
        #pragma unroll
        for (int j = 0; j < U; ++j) {
          lstm_update(owndot(cur[j]));
          if (gt == 0) lds_h0[p][j][ch] = hs;
        }
        #pragma unroll
        for (int j = 0; j < U; ++j) { cur[j] = nxt[j]; nxt[j] = ld[j]; }
      }
    } else if (wave == 1) {
      if (s >= 1 && s <= NS) {
        #pragma unroll
        for (int j = 0; j < U; ++j) {
          // broadcast (same-address) vector read of h0(s-1, step j)
          const float4* hp = (const float4*)&lds_h0[q][j][0];
          float4 h0v = hp[0], h1v = hp[1], h2v = hp[2], h3v = hp[3];
          float hin[16] = {h0v.x,h0v.y,h0v.z,h0v.w, h1v.x,h1v.y,h1v.z,h1v.w,
                           h2v.x,h2v.y,h2v.z,h2v.w, h3v.x,h3v.y,h3v.z,h3v.w};
          lstm_update(owndot(indot(hin)));
          if (gt == 0) lds_h1[p][j][ch] = hs;
        }
      }
    } else {
      if (s >= 2) {
        #pragma unroll
        for (int j = 0; j < U; ++j) {
          const float4* hp = (const float4*)&lds_h1[q][j][0];
          float4 h0v = hp[0], h1v = hp[1], h2v = hp[2], h3v = hp[3];
          float hin[16] = {h0v.x,h0v.y,h0v.z,h0v.w, h1v.x,h1v.y,h1v.z,h1v.w,
                           h2v.x,h2v.y,h2v.z,h2v.w, h3v.x,h3v.y,h3v.z,h3v.w};
          lstm_update(owndot(indot(hin)));
          const int t = (s - 2)*U + j;
          if (t < len) {
            if (gt == 0) h2row[t*16 + ch] = hs;
            sum += hs; sq += hs*hs;
          }
        }
      }
    }
    __syncthreads();
  }

  for (int idx = len*16 + tid; idx < TT*16; idx += 192)
    h2row[idx] = 0.f;

  if (wave == 2 && gt == 0) {
    atomicAdd(&accum[ch],      sum);
    atomicAdd(&accum[16 + ch], sq);
  }
}

// Fold BN (training stats incl. padding zeros) + gamma/beta into FC.
__global__ void prep_k(const float* __restrict__ accum,
                       const float* __restrict__ gamma, const float* __restrict__ beta,
                       const float* __restrict__ fcw, const float* __restrict__ fcb,
                       float* __restrict__ coef)
{
  const int lane = threadIdx.x;
  const int o = lane >> 4, c = lane & 15;
  const float inv_n = 1.0f / NF;
  float mean = accum[c] * inv_n;
  float var  = accum[16 + c] * inv_n - mean*mean;
  float s  = gamma[c] * rsqrtf(var + 1e-5f);
  float tb = beta[c] - mean * s;
  float woc = fcw[o*16 + c];
  coef[lane] = s * woc;
  float term = tb * woc;
  #pragma unroll
  for (int off = 1; off < 16; off <<= 1) term += __shfl_xor(term, off, 16);
  if (c == 0) coef[64 + o] = fcb[o] + term;
}

__global__ __launch_bounds__(256) void finalize_k(
    const float* __restrict__ h2buf, const float* __restrict__ coef,
    float* __restrict__ out)
{
  const int r = blockIdx.x * 256 + threadIdx.x;
  const float4* hp = (const float4*)(h2buf + (size_t)r * 16);
  float4 v0 = hp[0], v1 = hp[1], v2 = hp[2], v3 = hp[3];
  float hv[16] = {v0.x,v0.y,v0.z,v0.w, v1.x,v1.y,v1.z,v1.w,
                  v2.x,v2.y,v2.z,v2.w, v3.x,v3.y,v3.z,v3.w};
  float4 o4;
  float* op = &o4.x;
  #pragma unroll
  for (int o = 0; o < 4; ++o) {
    float a = coef[64 + o];
    #pragma unroll
    for (int c = 0; c < 16; ++c) a += coef[o*16 + c] * hv[c];
    op[o] = a;
  }
  ((float4*)out)[r] = o4;
}

extern "C" void kernel_launch(void* const* d_in, const int* in_sizes, int n_in,
                              void* d_out, int out_size, void* d_ws, size_t ws_size,
                              hipStream_t stream)
{
  const float* x     = (const float*)d_in[0];
  const int* lengths = (const int*)d_in[1];
  const float* W_ih0 = (const float*)d_in[2];
  const float* W_hh0 = (const float*)d_in[3];
  const float* b_ih0 = (const float*)d_in[4];
  const float* b_hh0 = (const float*)d_in[5];
  const float* W_ih1 = (const float*)d_in[6];
  const float* W_hh1 = (const float*)d_in[7];
  const float* b_ih1 = (const float*)d_in[8];
  const float* b_hh1 = (const float*)d_in[9];
  const float* W_ih2 = (const float*)d_in[10];
  const float* W_hh2 = (const float*)d_in[11];
  const float* b_ih2 = (const float*)d_in[12];
  const float* b_hh2 = (const float*)d_in[13];
  const float* gamma = (const float*)d_in[14];
  const float* beta  = (const float*)d_in[15];
  const float* fcw   = (const float*)d_in[16];
  const float* fcb   = (const float*)d_in[17];
  float* out = (float*)d_out;

  float* ws    = (float*)d_ws;
  float* xg0   = ws;                        // B*T*64 floats (128 MB)
  float* h2    = ws + 33554432;             // B*T*16 floats (32 MB)
  float* accum = ws + 33554432 + 8388608;   // 32 floats
  float* coef  = accum + 32;                // 68 floats

  hipLaunchKernelGGL(zero_accum_k, dim3(1), dim3(32), 0, stream, accum);
  hipLaunchKernelGGL(xg0_gemm_k, dim3(2048), dim3(256), 0, stream,
                     x, W_ih0, b_ih0, b_hh0, xg0);
  hipLaunchKernelGGL(lstm_scan_pipe_k, dim3(256), dim3(192), 0, stream,
                     xg0, lengths, W_hh0, W_ih1, W_hh1, b_ih1, b_hh1,
                     W_ih2, W_hh2, b_ih2, b_hh2, h2, accum);
  hipLaunchKernelGGL(prep_k, dim3(1), dim3(64), 0, stream,
                     accum, gamma, beta, fcw, fcb, coef);
  hipLaunchKernelGGL(finalize_k, dim3(2048), dim3(256), 0, stream, h2, coef, out);
}

// Round 7
// 784.109 us; speedup vs baseline: 1.0696x; 1.0696x over previous
//
#include <hip/hip_runtime.h>
#include <math.h>

#define TT 2048
#define BBATCH 256
#define DDIM 57
#define NROWS (BBATCH*TT)
#define NF 524288.0f
#define U 8

#define K1 (-1.4426950408889634f)   // -log2(e)   : sigmoid rows (i,f,o)
#define K2 (-2.8853900817779268f)   // -2 log2(e) : tanh rows (g) and tanh(c)

__device__ __forceinline__ float bcastl(float v, int k) {
  return __uint_as_float((unsigned)__builtin_amdgcn_readlane((int)__float_as_uint(v), k));
}
__device__ __forceinline__ float rcpf(float x) { return __builtin_amdgcn_rcpf(x); }
__device__ __forceinline__ float exp2f_(float x) { return __builtin_amdgcn_exp2f(x); }

// quad_perm broadcast: all 4 lanes of each quad get lane (PAT&3)'s value.
template<int PAT>
__device__ __forceinline__ float quadb(float v) {
  return __int_as_float(__builtin_amdgcn_update_dpp(0, __float_as_int(v), PAT, 0xF, 0xF, true));
}

__global__ void zero_accum_k(float* accum) {
  accum[threadIdx.x] = 0.f;
}

// xg0[r, lane] = fac(g) * (dot(x[r,:], W_ih0[g,:]) + b_ih0[g]+b_hh0[g])
// g = (lane&3)*16 + (lane>>2); fac = K2 for g rows, K1 else (folds exp2 conv).
__global__ __launch_bounds__(256) void xg0_gemm_k(
    const float* __restrict__ x, const float* __restrict__ Wih,
    const float* __restrict__ bih, const float* __restrict__ bhh,
    float* __restrict__ xg0)
{
  const int lane = threadIdx.x & 63;
  const int g = (lane & 3) * 16 + (lane >> 2);
  const float fac = ((lane & 3) == 2) ? K2 : K1;
  const int wid  = blockIdx.x * (blockDim.x >> 6) + (threadIdx.x >> 6);
  const int nw   = gridDim.x * (blockDim.x >> 6);
  float w[DDIM];
  #pragma unroll
  for (int d = 0; d < DDIM; ++d) w[d] = fac * Wih[g*DDIM + d];
  const float bias = fac * (bih[g] + bhh[g]);

  int r = wid;
  float xv = 0.f;
  if (r < NROWS && lane < DDIM)
    xv = x[(size_t)__builtin_amdgcn_readfirstlane(r) * DDIM + lane];
  for (; r < NROWS; r += nw) {
    const int rn = r + nw;
    float xn = 0.f;
    if (rn < NROWS && lane < DDIM)                  // prefetch next row
      xn = x[(size_t)__builtin_amdgcn_readfirstlane(rn) * DDIM + lane];
    float a0 = bias, a1 = 0.f, a2 = 0.f, a3 = 0.f;
    #pragma unroll
    for (int d = 0; d < 56; d += 4) {
      a0 += w[d]   * bcastl(xv, d);
      a1 += w[d+1] * bcastl(xv, d+1);
      a2 += w[d+2] * bcastl(xv, d+2);
      a3 += w[d+3] * bcastl(xv, d+3);
    }
    a0 += w[56] * bcastl(xv, 56);
    xg0[(size_t)__builtin_amdgcn_readfirstlane(r) * 64 + lane] = (a0 + a1) + (a2 + a3);
    xv = xn;
  }
}

// Layer-pipelined scan, U=8 steps/slot, 3 waves/block (wave w = layer w,
// lagging w slots). Lane layout: ch=lane>>2, gate=lane&3 (i,f,g,o).
// KEY (R7): waves 1/2 precompute ALL U input-dots xin[j] right after the
// barrier (hin depends only on the previous slot's LDS buffer, not on hs) —
// the per-step serial chain is then owndot(seed=xin[j]) -> act -> c -> h,
// identical to wave0. Previously indot+LDS-read sat ON the chain (~185 cyc).
__global__ __launch_bounds__(192, 1) void lstm_scan_pipe_k(
    const float* __restrict__ xg0,
    const int*   __restrict__ lengths,
    const float* __restrict__ Whh0,
    const float* __restrict__ Wih1, const float* __restrict__ Whh1,
    const float* __restrict__ bih1, const float* __restrict__ bhh1,
    const float* __restrict__ Wih2, const float* __restrict__ Whh2,
    const float* __restrict__ bih2, const float* __restrict__ bhh2,
    float* __restrict__ h2buf, float* __restrict__ accum)
{
  const int tid  = threadIdx.x;
  const int wave = tid >> 6;
  const int lane = tid & 63;
  const int gt   = lane & 3;       // 0=i 1=f 2=g 3=o
  const int ch   = lane >> 2;      // channel 0..15
  const int g    = gt*16 + ch;     // weight row (PyTorch i,f,g,o blocks)
  const int b    = blockIdx.x;
  const int len  = lengths[b];
  const bool isg = (gt == 2);
  const float fac = isg ? K2 : K1;
  const float mg = isg ? 2.f : 1.f;     // act = s*mg + ag
  const float ag = isg ? -1.f : 0.f;

  __shared__ float lds_h0[2][U][16];
  __shared__ float lds_h1[2][U][16];

  float wa[16], wb[16];
  float bias = 0.f;
  if (wave == 0) {
    #pragma unroll
    for (int k = 0; k < 16; ++k) { wb[k] = fac * Whh0[g*16 + k]; wa[k] = 0.f; }
  } else if (wave == 1) {
    #pragma unroll
    for (int k = 0; k < 16; ++k) { wa[k] = fac * Wih1[g*16 + k]; wb[k] = fac * Whh1[g*16 + k]; }
    bias = fac * (bih1[g] + bhh1[g]);
  } else {
    #pragma unroll
    for (int k = 0; k < 16; ++k) { wa[k] = fac * Wih2[g*16 + k]; wb[k] = fac * Whh2[g*16 + k]; }
    bias = fac * (bih2[g] + bhh2[g]);
  }

  float hs = 0.f, cs = 0.f;
  float sum = 0.f, sq = 0.f;
  const int base = b*TT*64 + lane;
  float* __restrict__ h2row = h2buf + (size_t)b*TT*16;

  auto lstm_update = [&](float dot) {
    float s   = rcpf(1.f + exp2f_(dot));
    float act = fmaf(s, mg, ag);          // sigmoid, or tanh for g-gate
    float gi = quadb<0x00>(act);
    float gf = quadb<0x55>(act);
    float gg = quadb<0xAA>(act);
    float go = quadb<0xFF>(act);
    cs = fmaf(gf, cs, gi*gg);
    float r = rcpf(1.f + exp2f_(cs * K2));
    hs = go * fmaf(2.f, r, -1.f);         // go * tanh(cs)
  };
  auto owndot = [&](float seed) {         // seed + Whh' . h_own (readlane)
    float a0 = seed, a1 = 0.f, a2 = 0.f, a3 = 0.f;
    #pragma unroll
    for (int k = 0; k < 16; k += 4) {     // h[k] lives on lane 4k
      a0 += wb[k]   * bcastl(hs, 4*k);
      a1 += wb[k+1] * bcastl(hs, 4*k+4);
      a2 += wb[k+2] * bcastl(hs, 4*k+8);
      a3 += wb[k+3] * bcastl(hs, 4*k+12);
    }
    return (a0 + a1) + (a2 + a3);
  };
  // bias + Wih' . hin, hin as full register vector (no readlane, off-chain)
  auto indot = [&](const float* hin) {
    float a0 = bias, a1 = 0.f, a2 = 0.f, a3 = 0.f;
    #pragma unroll
    for (int k = 0; k < 16; k += 4) {
      a0 += wa[k]   * hin[k];
      a1 += wa[k+1] * hin[k+1];
      a2 += wa[k+2] * hin[k+2];
      a3 += wa[k+3] * hin[k+3];
    }
    return (a0 + a1) + (a2 + a3);
  };

  const int NS = (len + U - 1) / U;
  const int S  = NS + 2;

  float cur[U], nxt[U];
  if (wave == 0) {
    #pragma unroll
    for (int j = 0; j < U; ++j) cur[j] = xg0[base + j*64];
    #pragma unroll
    for (int j = 0; j < U; ++j) {
      int ip = U + j; ip = ip > TT-1 ? TT-1 : ip;
      nxt[j] = xg0[base + ip*64];
    }
  }

  for (int s = 0; s < S; ++s) {
    const int p = s & 1, q = p ^ 1;
    if (wave == 0) {
      if (s < NS) {
        float ld[U];
        #pragma unroll
        for (int j = 0; j < U; ++j) {
          int ip = (s + 2)*U + j; ip = ip > TT-1 ? TT-1 : ip;
          ld[j] = xg0[base + ip*64];      // slot s+2; lands well before use
        }
        #pragma unroll
        for (int j = 0; j < U; ++j) {
          lstm_update(owndot(cur[j]));
          if (gt == 0) lds_h0[p][j][ch] = hs;
        }
        #pragma unroll
        for (int j = 0; j < U; ++j) { cur[j] = nxt[j]; nxt[j] = ld[j]; }
      }
    } else if (wave == 1) {
      if (s >= 1 && s <= NS) {
        float xin[U];
        #pragma unroll
        for (int j = 0; j < U; ++j) {     // ALL input-dots up front, off-chain
          const float4* hp = (const float4*)&lds_h0[q][j][0];
          float4 h0v = hp[0], h1v = hp[1], h2v = hp[2], h3v = hp[3];
          float hin[16] = {h0v.x,h0v.y,h0v.z,h0v.w, h1v.x,h1v.y,h1v.z,h1v.w,
                           h2v.x,h2v.y,h2v.z,h2v.w, h3v.x,h3v.y,h3v.z,h3v.w};
          xin[j] = indot(hin);
        }
        #pragma unroll
        for (int j = 0; j < U; ++j) {     // serial chain: same as wave0
          lstm_update(owndot(xin[j]));
          if (gt == 0) lds_h1[p][j][ch] = hs;
        }
      }
    } else {
      if (s >= 2) {
        float xin[U];
        #pragma unroll
        for (int j = 0; j < U; ++j) {
          const float4* hp = (const float4*)&lds_h1[q][j][0];
          float4 h0v = hp[0], h1v = hp[1], h2v = hp[2], h3v = hp[3];
          float hin[16] = {h0v.x,h0v.y,h0v.z,h0v.w, h1v.x,h1v.y,h1v.z,h1v.w,
                           h2v.x,h2v.y,h2v.z,h2v.w, h3v.x,h3v.y,h3v.z,h3v.w};
          xin[j] = indot(hin);
        }
        #pragma unroll
        for (int j = 0; j < U; ++j) {
          lstm_update(owndot(xin[j]));
          const int t = (s - 2)*U + j;
          if (t < len) {
            if (gt == 0) h2row[t*16 + ch] = hs;
            sum += hs; sq += hs*hs;
          }
        }
      }
    }
    __syncthreads();
  }

  for (int idx = len*16 + tid; idx < TT*16; idx += 192)
    h2row[idx] = 0.f;

  if (wave == 2 && gt == 0) {
    atomicAdd(&accum[ch],      sum);
    atomicAdd(&accum[16 + ch], sq);
  }
}

// Fold BN (training stats incl. padding zeros) + gamma/beta into FC.
__global__ void prep_k(const float* __restrict__ accum,
                       const float* __restrict__ gamma, const float* __restrict__ beta,
                       const float* __restrict__ fcw, const float* __restrict__ fcb,
                       float* __restrict__ coef)
{
  const int lane = threadIdx.x;
  const int o = lane >> 4, c = lane & 15;
  const float inv_n = 1.0f / NF;
  float mean = accum[c] * inv_n;
  float var  = accum[16 + c] * inv_n - mean*mean;
  float s  = gamma[c] * rsqrtf(var + 1e-5f);
  float tb = beta[c] - mean * s;
  float woc = fcw[o*16 + c];
  coef[lane] = s * woc;
  float term = tb * woc;
  #pragma unroll
  for (int off = 1; off < 16; off <<= 1) term += __shfl_xor(term, off, 16);
  if (c == 0) coef[64 + o] = fcb[o] + term;
}

__global__ __launch_bounds__(256) void finalize_k(
    const float* __restrict__ h2buf, const float* __restrict__ coef,
    float* __restrict__ out)
{
  const int r = blockIdx.x * 256 + threadIdx.x;
  const float4* hp = (const float4*)(h2buf + (size_t)r * 16);
  float4 v0 = hp[0], v1 = hp[1], v2 = hp[2], v3 = hp[3];
  float hv[16] = {v0.x,v0.y,v0.z,v0.w, v1.x,v1.y,v1.z,v1.w,
                  v2.x,v2.y,v2.z,v2.w, v3.x,v3.y,v3.z,v3.w};
  float4 o4;
  float* op = &o4.x;
  #pragma unroll
  for (int o = 0; o < 4; ++o) {
    float a = coef[64 + o];
    #pragma unroll
    for (int c = 0; c < 16; ++c) a += coef[o*16 + c] * hv[c];
    op[o] = a;
  }
  ((float4*)out)[r] = o4;
}

extern "C" void kernel_launch(void* const* d_in, const int* in_sizes, int n_in,
                              void* d_out, int out_size, void* d_ws, size_t ws_size,
                              hipStream_t stream)
{
  const float* x     = (const float*)d_in[0];
  const int* lengths = (const int*)d_in[1];
  const float* W_ih0 = (const float*)d_in[2];
  const float* W_hh0 = (const float*)d_in[3];
  const float* b_ih0 = (const float*)d_in[4];
  const float* b_hh0 = (const float*)d_in[5];
  const float* W_ih1 = (const float*)d_in[6];
  const float* W_hh1 = (const float*)d_in[7];
  const float* b_ih1 = (const float*)d_in[8];
  const float* b_hh1 = (const float*)d_in[9];
  const float* W_ih2 = (const float*)d_in[10];
  const float* W_hh2 = (const float*)d_in[11];
  const float* b_ih2 = (const float*)d_in[12];
  const float* b_hh2 = (const float*)d_in[13];
  const float* gamma = (const float*)d_in[14];
  const float* beta  = (const float*)d_in[15];
  const float* fcw   = (const float*)d_in[16];
  const float* fcb   = (const float*)d_in[17];
  float* out = (float*)d_out;

  float* ws    = (float*)d_ws;
  float* xg0   = ws;                        // B*T*64 floats (128 MB)
  float* h2    = ws + 33554432;             // B*T*16 floats (32 MB)
  float* accum = ws + 33554432 + 8388608;   // 32 floats
  float* coef  = accum + 32;                // 68 floats

  hipLaunchKernelGGL(zero_accum_k, dim3(1), dim3(32), 0, stream, accum);
  hipLaunchKernelGGL(xg0_gemm_k, dim3(2048), dim3(256), 0, stream,
                     x, W_ih0, b_ih0, b_hh0, xg0);
  hipLaunchKernelGGL(lstm_scan_pipe_k, dim3(256), dim3(192), 0, stream,
                     xg0, lengths, W_hh0, W_ih1, W_hh1, b_ih1, b_hh1,
                     W_ih2, W_hh2, b_ih2, b_hh2, h2, accum);
  hipLaunchKernelGGL(prep_k, dim3(1), dim3(64), 0, stream,
                     accum, gamma, beta, fcw, fcb, coef);
  hipLaunchKernelGGL(finalize_k, dim3(2048), dim3(256), 0, stream, h2, coef, out);
}

// Round 8
// 691.318 us; speedup vs baseline: 1.2131x; 1.1342x over previous
//
#include <hip/hip_runtime.h>
#include <math.h>

#define TT 2048
#define BBATCH 256
#define DDIM 57
#define NROWS (BBATCH*TT)
#define NF 524288.0f
#define U 8

#define K1 (-1.4426950408889634f)   // -log2(e)   : sigmoid rows (i,f,o)
#define K2 (-2.8853900817779268f)   // -2 log2(e) : tanh rows (g) and tanh(c)

__device__ __forceinline__ float bcastl(float v, int k) {
  return __uint_as_float((unsigned)__builtin_amdgcn_readlane((int)__float_as_uint(v), k));
}
__device__ __forceinline__ float rcpf(float x) { return __builtin_amdgcn_rcpf(x); }
__device__ __forceinline__ float exp2f_(float x) { return __builtin_amdgcn_exp2f(x); }

// quad_perm broadcast: all 4 lanes of each quad get lane (PAT&3)'s value.
template<int PAT>
__device__ __forceinline__ float quadb(float v) {
  return __int_as_float(__builtin_amdgcn_update_dpp(0, __float_as_int(v), PAT, 0xF, 0xF, true));
}

__global__ void zero_accum_k(float* accum) {
  accum[threadIdx.x] = 0.f;
}

// xg0[r, lane] = fac(g) * (dot(x[r,:], W_ih0[g,:]) + b_ih0[g]+b_hh0[g])
// g = (lane&3)*16 + (lane>>2); fac = K2 for g rows, K1 else (folds exp2 conv).
__global__ __launch_bounds__(256) void xg0_gemm_k(
    const float* __restrict__ x, const float* __restrict__ Wih,
    const float* __restrict__ bih, const float* __restrict__ bhh,
    float* __restrict__ xg0)
{
  const int lane = threadIdx.x & 63;
  const int g = (lane & 3) * 16 + (lane >> 2);
  const float fac = ((lane & 3) == 2) ? K2 : K1;
  const int wid  = blockIdx.x * (blockDim.x >> 6) + (threadIdx.x >> 6);
  const int nw   = gridDim.x * (blockDim.x >> 6);
  float w[DDIM];
  #pragma unroll
  for (int d = 0; d < DDIM; ++d) w[d] = fac * Wih[g*DDIM + d];
  const float bias = fac * (bih[g] + bhh[g]);

  int r = wid;
  float xv = 0.f;
  if (r < NROWS && lane < DDIM)
    xv = x[(size_t)__builtin_amdgcn_readfirstlane(r) * DDIM + lane];
  for (; r < NROWS; r += nw) {
    const int rn = r + nw;
    float xn = 0.f;
    if (rn < NROWS && lane < DDIM)                  // prefetch next row
      xn = x[(size_t)__builtin_amdgcn_readfirstlane(rn) * DDIM + lane];
    float a0 = bias, a1 = 0.f, a2 = 0.f, a3 = 0.f;
    #pragma unroll
    for (int d = 0; d < 56; d += 4) {
      a0 += w[d]   * bcastl(xv, d);
      a1 += w[d+1] * bcastl(xv, d+1);
      a2 += w[d+2] * bcastl(xv, d+2);
      a3 += w[d+3] * bcastl(xv, d+3);
    }
    a0 += w[56] * bcastl(xv, 56);
    xg0[(size_t)__builtin_amdgcn_readfirstlane(r) * 64 + lane] = (a0 + a1) + (a2 + a3);
    xv = xn;
  }
}

// Layer-pipelined scan, U=8 steps/slot, 3 waves/block (wave w = layer w,
// lagging w slots). Lane layout: ch=lane>>2, gate=lane&3 (i,f,g,o).
// R8: owndot hoists ALL 16 readlane broadcasts into hb[16] BEFORE the FMA
// tree — pays broadcast latency once, not 16x (R7 showed the chain cost
// lives inside owndot). cs kept pre-scaled by K2 (csK) to drop a chain mul.
__global__ __launch_bounds__(192, 1) void lstm_scan_pipe_k(
    const float* __restrict__ xg0,
    const int*   __restrict__ lengths,
    const float* __restrict__ Whh0,
    const float* __restrict__ Wih1, const float* __restrict__ Whh1,
    const float* __restrict__ bih1, const float* __restrict__ bhh1,
    const float* __restrict__ Wih2, const float* __restrict__ Whh2,
    const float* __restrict__ bih2, const float* __restrict__ bhh2,
    float* __restrict__ h2buf, float* __restrict__ accum)
{
  const int tid  = threadIdx.x;
  const int wave = tid >> 6;
  const int lane = tid & 63;
  const int gt   = lane & 3;       // 0=i 1=f 2=g 3=o
  const int ch   = lane >> 2;      // channel 0..15
  const int g    = gt*16 + ch;     // weight row (PyTorch i,f,g,o blocks)
  const int b    = blockIdx.x;
  const int len  = lengths[b];
  const bool isg = (gt == 2);
  const float fac = isg ? K2 : K1;
  const float mg = isg ? 2.f : 1.f;     // act = s*mg + ag
  const float ag = isg ? -1.f : 0.f;

  __shared__ float lds_h0[2][U][16];
  __shared__ float lds_h1[2][U][16];

  float wa[16], wb[16];
  float bias = 0.f;
  if (wave == 0) {
    #pragma unroll
    for (int k = 0; k < 16; ++k) { wb[k] = fac * Whh0[g*16 + k]; wa[k] = 0.f; }
  } else if (wave == 1) {
    #pragma unroll
    for (int k = 0; k < 16; ++k) { wa[k] = fac * Wih1[g*16 + k]; wb[k] = fac * Whh1[g*16 + k]; }
    bias = fac * (bih1[g] + bhh1[g]);
  } else {
    #pragma unroll
    for (int k = 0; k < 16; ++k) { wa[k] = fac * Wih2[g*16 + k]; wb[k] = fac * Whh2[g*16 + k]; }
    bias = fac * (bih2[g] + bhh2[g]);
  }

  float hs = 0.f, csK = 0.f;            // csK = K2 * c  (pre-scaled recurrence)
  float sum = 0.f, sq = 0.f;
  const int base = b*TT*64 + lane;
  float* __restrict__ h2row = h2buf + (size_t)b*TT*16;

  auto lstm_update = [&](float dot) {
    float s   = rcpf(1.f + exp2f_(dot));
    float act = fmaf(s, mg, ag);          // sigmoid, or tanh for g-gate
    float gi = quadb<0x00>(act);
    float gf = quadb<0x55>(act);
    float gg = quadb<0xAA>(act);
    float go = quadb<0xFF>(act);
    csK = fmaf(gf, csK, (K2 * gg) * gi);  // K2*(f*c + i*g)
    float r = rcpf(1.f + exp2f_(csK));
    hs = go * fmaf(2.f, r, -1.f);         // go * tanh(c)
  };
  auto owndot = [&](float seed) {         // seed + Whh' . h_own
    float hb[16];                         // ALL broadcasts first (uniform->SGPR)
    #pragma unroll
    for (int k = 0; k < 16; ++k) hb[k] = bcastl(hs, 4*k);
    float a0 = seed, a1 = 0.f, a2 = 0.f, a3 = 0.f;
    #pragma unroll
    for (int k = 0; k < 16; k += 4) {
      a0 += wb[k]   * hb[k];
      a1 += wb[k+1] * hb[k+1];
      a2 += wb[k+2] * hb[k+2];
      a3 += wb[k+3] * hb[k+3];
    }
    return (a0 + a1) + (a2 + a3);
  };
  // bias + Wih' . hin, hin as full register vector (no readlane, off-chain)
  auto indot = [&](const float* hin) {
    float a0 = bias, a1 = 0.f, a2 = 0.f, a3 = 0.f;
    #pragma unroll
    for (int k = 0; k < 16; k += 4) {
      a0 += wa[k]   * hin[k];
      a1 += wa[k+1] * hin[k+1];
      a2 += wa[k+2] * hin[k+2];
      a3 += wa[k+3] * hin[k+3];
    }
    return (a0 + a1) + (a2 + a3);
  };

  const int NS = (len + U - 1) / U;
  const int S  = NS + 2;

  float cur[U], nxt[U];
  if (wave == 0) {
    #pragma unroll
    for (int j = 0; j < U; ++j) cur[j] = xg0[base + j*64];
    #pragma unroll
    for (int j = 0; j < U; ++j) {
      int ip = U + j; ip = ip > TT-1 ? TT-1 : ip;
      nxt[j] = xg0[base + ip*64];
    }
  }

  for (int s = 0; s < S; ++s) {
    const int p = s & 1, q = p ^ 1;
    if (wave == 0) {
      if (s < NS) {
        float ld[U];
        #pragma unroll
        for (int j = 0; j < U; ++j) {
          int ip = (s + 2)*U + j; ip = ip > TT-1 ? TT-1 : ip;
          ld[j] = xg0[base + ip*64];      // slot s+2; lands well before use
        }
        #pragma unroll
        for (int j = 0; j < U; ++j) {
          lstm_update(owndot(cur[j]));
          if (gt == 0) lds_h0[p][j][ch] = hs;
        }
        #pragma unroll
        for (int j = 0; j < U; ++j) { cur[j] = nxt[j]; nxt[j] = ld[j]; }
      }
    } else if (wave == 1) {
      if (s >= 1 && s <= NS) {
        float xin[U];
        #pragma unroll
        for (int j = 0; j < U; ++j) {     // ALL input-dots up front, off-chain
          const float4* hp = (const float4*)&lds_h0[q][j][0];
          float4 h0v = hp[0], h1v = hp[1], h2v = hp[2], h3v = hp[3];
          float hin[16] = {h0v.x,h0v.y,h0v.z,h0v.w, h1v.x,h1v.y,h1v.z,h1v.w,
                           h2v.x,h2v.y,h2v.z,h2v.w, h3v.x,h3v.y,h3v.z,h3v.w};
          xin[j] = indot(hin);
        }
        #pragma unroll
        for (int j = 0; j < U; ++j) {     // serial chain: same as wave0
          lstm_update(owndot(xin[j]));
          if (gt == 0) lds_h1[p][j][ch] = hs;
        }
      }
    } else {
      if (s >= 2) {
        float xin[U];
        #pragma unroll
        for (int j = 0; j < U; ++j) {
          const float4* hp = (const float4*)&lds_h1[q][j][0];
          float4 h0v = hp[0], h1v = hp[1], h2v = hp[2], h3v = hp[3];
          float hin[16] = {h0v.x,h0v.y,h0v.z,h0v.w, h1v.x,h1v.y,h1v.z,h1v.w,
                           h2v.x,h2v.y,h2v.z,h2v.w, h3v.x,h3v.y,h3v.z,h3v.w};
          xin[j] = indot(hin);
        }
        #pragma unroll
        for (int j = 0; j < U; ++j) {
          lstm_update(owndot(xin[j]));
          const int t = (s - 2)*U + j;
          if (t < len) {
            if (gt == 0) h2row[t*16 + ch] = hs;
            sum += hs; sq += hs*hs;
          }
        }
      }
    }
    __syncthreads();
  }

  for (int idx = len*16 + tid; idx < TT*16; idx += 192)
    h2row[idx] = 0.f;

  if (wave == 2 && gt == 0) {
    atomicAdd(&accum[ch],      sum);
    atomicAdd(&accum[16 + ch], sq);
  }
}

// Fold BN (training stats incl. padding zeros) + gamma/beta into FC.
__global__ void prep_k(const float* __restrict__ accum,
                       const float* __restrict__ gamma, const float* __restrict__ beta,
                       const float* __restrict__ fcw, const float* __restrict__ fcb,
                       float* __restrict__ coef)
{
  const int lane = threadIdx.x;
  const int o = lane >> 4, c = lane & 15;
  const float inv_n = 1.0f / NF;
  float mean = accum[c] * inv_n;
  float var  = accum[16 + c] * inv_n - mean*mean;
  float s  = gamma[c] * rsqrtf(var + 1e-5f);
  float tb = beta[c] - mean * s;
  float woc = fcw[o*16 + c];
  coef[lane] = s * woc;
  float term = tb * woc;
  #pragma unroll
  for (int off = 1; off < 16; off <<= 1) term += __shfl_xor(term, off, 16);
  if (c == 0) coef[64 + o] = fcb[o] + term;
}

__global__ __launch_bounds__(256) void finalize_k(
    const float* __restrict__ h2buf, const float* __restrict__ coef,
    float* __restrict__ out)
{
  const int r = blockIdx.x * 256 + threadIdx.x;
  const float4* hp = (const float4*)(h2buf + (size_t)r * 16);
  float4 v0 = hp[0], v1 = hp[1], v2 = hp[2], v3 = hp[3];
  float hv[16] = {v0.x,v0.y,v0.z,v0.w, v1.x,v1.y,v1.z,v1.w,
                  v2.x,v2.y,v2.z,v2.w, v3.x,v3.y,v3.z,v3.w};
  float4 o4;
  float* op = &o4.x;
  #pragma unroll
  for (int o = 0; o < 4; ++o) {
    float a = coef[64 + o];
    #pragma unroll
    for (int c = 0; c < 16; ++c) a += coef[o*16 + c] * hv[c];
    op[o] = a;
  }
  ((float4*)out)[r] = o4;
}

extern "C" void kernel_launch(void* const* d_in, const int* in_sizes, int n_in,
                              void* d_out, int out_size, void* d_ws, size_t ws_size,
                              hipStream_t stream)
{
  const float* x     = (const float*)d_in[0];
  const int* lengths = (const int*)d_in[1];
  const float* W_ih0 = (const float*)d_in[2];
  const float* W_hh0 = (const float*)d_in[3];
  const float* b_ih0 = (const float*)d_in[4];
  const float* b_hh0 = (const float*)d_in[5];
  const float* W_ih1 = (const float*)d_in[6];
  const float* W_hh1 = (const float*)d_in[7];
  const float* b_ih1 = (const float*)d_in[8];
  const float* b_hh1 = (const float*)d_in[9];
  const float* W_ih2 = (const float*)d_in[10];
  const float* W_hh2 = (const float*)d_in[11];
  const float* b_ih2 = (const float*)d_in[12];
  const float* b_hh2 = (const float*)d_in[13];
  const float* gamma = (const float*)d_in[14];
  const float* beta  = (const float*)d_in[15];
  const float* fcw   = (const float*)d_in[16];
  const float* fcb   = (const float*)d_in[17];
  float* out = (float*)d_out;

  float* ws    = (float*)d_ws;
  float* xg0   = ws;                        // B*T*64 floats (128 MB)
  float* h2    = ws + 33554432;             // B*T*16 floats (32 MB)
  float* accum = ws + 33554432 + 8388608;   // 32 floats
  float* coef  = accum + 32;                // 68 floats

  hipLaunchKernelGGL(zero_accum_k, dim3(1), dim3(32), 0, stream, accum);
  hipLaunchKernelGGL(xg0_gemm_k, dim3(2048), dim3(256), 0, stream,
                     x, W_ih0, b_ih0, b_hh0, xg0);
  hipLaunchKernelGGL(lstm_scan_pipe_k, dim3(256), dim3(192), 0, stream,
                     xg0, lengths, W_hh0, W_ih1, W_hh1, b_ih1, b_hh1,
                     W_ih2, W_hh2, b_ih2, b_hh2, h2, accum);
  hipLaunchKernelGGL(prep_k, dim3(1), dim3(64), 0, stream,
                     accum, gamma, beta, fcw, fcb, coef);
  hipLaunchKernelGGL(finalize_k, dim3(2048), dim3(256), 0, stream, h2, coef, out);
}